// Round 12
// baseline (381.026 us; speedup 1.0000x reference)
//
#include <hip/hip_runtime.h>

// RBF: out[n,m] = exp(-max(||x_n||^2 + ||p_m||^2 - 2 x.p, 0)), gamma=1.
// N=131072, M=512, D=64, fp32 in/out.
//
// No-LDS MFMA design:
//  - trunc-split x = xh + xl, p = ph + pl (bf16 + bf16 residual), in-register.
//  - cross = ph.xh + ph.xl + pl.xh (pl.xl dropped; ~3e-4 abs err in dist2,
//    threshold allows ~2e-2).
//  - SWAPPED operands: D = mfma(A=p_frag, B=x_frag) => C/D reg-dim = m
//    (output-minor) -> one float4 store per fragment (16 stores/thread).
//  - Fragments loaded straight from global (row = lane&15, 8 contiguous d at
//    (lane>>4)*8 + 32h) — L2/L3-hot; no LDS, no barriers, waves independent.
//  - Norms in-register: per-lane partial sums of squares during load, reduced
//    with shfl_xor(16,32); ps redistributed to the reg-dim mapping via shfl.
//  - XCD swizzle: 4 m-tiles sharing an x-tile -> same XCD (x/XCD = 4MB = L2).

#define N_PTS 131072
#define M_PROT 512
#define D_DIM 64

typedef __attribute__((ext_vector_type(8))) short short8;
typedef __attribute__((ext_vector_type(4))) float f32x4;

union FragU { uint u[4]; short8 s; };

// Load 8 contiguous floats, trunc-split to bf16 hi + bf16 lo, accumulate sum sq.
__device__ inline void load_split(const float* p, short8& hi, short8& lo, float& nrm) {
  const float4 a = *reinterpret_cast<const float4*>(p);
  const float4 b = *reinterpret_cast<const float4*>(p + 4);
  const float f[8] = {a.x, a.y, a.z, a.w, b.x, b.y, b.z, b.w};
  FragU H, L;
#pragma unroll
  for (int i = 0; i < 4; ++i) {
    const uint u0 = __float_as_uint(f[2 * i]);
    const uint u1 = __float_as_uint(f[2 * i + 1]);
    H.u[i] = (u0 >> 16) | (u1 & 0xFFFF0000u);
    const float l0 = f[2 * i]     - __uint_as_float(u0 & 0xFFFF0000u);
    const float l1 = f[2 * i + 1] - __uint_as_float(u1 & 0xFFFF0000u);
    L.u[i] = (__float_as_uint(l0) >> 16) | (__float_as_uint(l1) & 0xFFFF0000u);
    nrm = fmaf(f[2 * i], f[2 * i], nrm);
    nrm = fmaf(f[2 * i + 1], f[2 * i + 1], nrm);
  }
  hi = H.s;
  lo = L.s;
}

__global__ __launch_bounds__(256, 3)
void rbf_mfma(const float* __restrict__ x,
              const float* __restrict__ prot,
              float* __restrict__ out) {
  const int tid = threadIdx.x;
  const int lane = tid & 63;
  const int w = tid >> 6;

  // XCD-aware swizzle (4096 wgs, 8 XCDs, bijective since 4096%8==0):
  // XCD c gets contiguous wg range; m-tile fastest -> x-tile reused 4x in-L2.
  const int bid = blockIdx.x;
  const int wg = (bid & 7) * 512 + (bid >> 3);
  const int ntile = wg >> 2;
  const int mtile = wg & 3;
  // 2x2 waves cover the 128x128 block tile; each wave owns 64n x 64m.
  const int n0w = ntile * 128 + (w >> 1) * 64;
  const int m0w = mtile * 128 + (w & 1) * 64;

  const int lr = lane & 15;        // row within fragment (A-row m / B-col n)
  const int kg = (lane >> 4) * 8;  // this lane's k(d)-offset within a k=32 frag

  f32x4 acc[4][4];  // acc[fi(m)][fj(n)]
#pragma unroll
  for (int i = 0; i < 4; ++i)
#pragma unroll
    for (int j = 0; j < 4; ++j) acc[i][j] = (f32x4){0.f, 0.f, 0.f, 0.f};

  float ps_part[4] = {0.f, 0.f, 0.f, 0.f};  // sumsq of p-row (m0w+fi*16+lr)
  float xs_part[4] = {0.f, 0.f, 0.f, 0.f};  // sumsq of x-row (n0w+fj*16+lr)

#pragma unroll
  for (int h = 0; h < 2; ++h) {  // two k=32 halves of D=64
    short8 PH[4], PL[4], XH[4], XL[4];
#pragma unroll
    for (int fi = 0; fi < 4; ++fi) {
      const float* src = prot + (size_t)(m0w + fi * 16 + lr) * D_DIM + h * 32 + kg;
      load_split(src, PH[fi], PL[fi], ps_part[fi]);
    }
#pragma unroll
    for (int fj = 0; fj < 4; ++fj) {
      const float* src = x + (size_t)(n0w + fj * 16 + lr) * D_DIM + h * 32 + kg;
      load_split(src, XH[fj], XL[fj], xs_part[fj]);
    }
    // D[m][n] += ph.xh + ph.xl + pl.xh
#pragma unroll
    for (int fi = 0; fi < 4; ++fi)
#pragma unroll
      for (int fj = 0; fj < 4; ++fj)
        acc[fi][fj] = __builtin_amdgcn_mfma_f32_16x16x32_bf16(PH[fi], XH[fj], acc[fi][fj], 0, 0, 0);
#pragma unroll
    for (int fi = 0; fi < 4; ++fi)
#pragma unroll
      for (int fj = 0; fj < 4; ++fj)
        acc[fi][fj] = __builtin_amdgcn_mfma_f32_16x16x32_bf16(PH[fi], XL[fj], acc[fi][fj], 0, 0, 0);
#pragma unroll
    for (int fi = 0; fi < 4; ++fi)
#pragma unroll
      for (int fj = 0; fj < 4; ++fj)
        acc[fi][fj] = __builtin_amdgcn_mfma_f32_16x16x32_bf16(PL[fi], XH[fj], acc[fi][fj], 0, 0, 0);
  }

  // ---- norm reductions: full row sums on every lane ----
#pragma unroll
  for (int f = 0; f < 4; ++f) {
    ps_part[f] += __shfl_xor(ps_part[f], 16);
    ps_part[f] += __shfl_xor(ps_part[f], 32);
    xs_part[f] += __shfl_xor(xs_part[f], 16);
    xs_part[f] += __shfl_xor(xs_part[f], 32);
  }
  // ps holds ||p_(m0w+fi*16+lane&15)||^2; epilogue needs m = (lane>>4)*4+r.
  f32x4 psv[4];
#pragma unroll
  for (int fi = 0; fi < 4; ++fi)
#pragma unroll
    for (int r = 0; r < 4; ++r)
      psv[fi][r] = __shfl(ps_part[fi], (lane >> 4) * 4 + r);

  // ---- epilogue: C/D layout col(n)=lane&15, row(m)=(lane>>4)*4+reg ----
  // out[n][m]: m contiguous across regs -> one float4 store per fragment.
#pragma unroll
  for (int fi = 0; fi < 4; ++fi) {
#pragma unroll
    for (int fj = 0; fj < 4; ++fj) {
      const f32x4 c = acc[fi][fj];
      const float xsv = xs_part[fj];  // row n = n0w + fj*16 + (lane&15): this lane's value
      float4 e;
      e.x = __expf(fminf(fmaf(2.f, c[0], -xsv) - psv[fi][0], 0.f));
      e.y = __expf(fminf(fmaf(2.f, c[1], -xsv) - psv[fi][1], 0.f));
      e.z = __expf(fminf(fmaf(2.f, c[2], -xsv) - psv[fi][2], 0.f));
      e.w = __expf(fminf(fmaf(2.f, c[3], -xsv) - psv[fi][3], 0.f));
      float* addr = out + (size_t)(n0w + fj * 16 + lr) * M_PROT + m0w + fi * 16 + (lane >> 4) * 4;
      *reinterpret_cast<float4*>(addr) = e;
    }
  }
}

extern "C" void kernel_launch(void* const* d_in, const int* in_sizes, int n_in,
                              void* d_out, int out_size, void* d_ws, size_t ws_size,
                              hipStream_t stream) {
  const float* x = (const float*)d_in[0];
  const float* p = (const float*)d_in[1];
  float* out = (float*)d_out;
  (void)in_sizes; (void)n_in; (void)out_size; (void)d_ws; (void)ws_size;
  rbf_mfma<<<(N_PTS / 128) * (M_PROT / 128), 256, 0, stream>>>(x, p, out);
}

// Round 13
// 348.021 us; speedup vs baseline: 1.0948x; 1.0948x over previous
//
#include <hip/hip_runtime.h>

// RBF: out[n,m] = exp(-max(||x_n||^2 + ||p_m||^2 - 2 x.p, 0)), gamma=1.
// N=131072, M=512, D=64, fp32 in/out.
//
// Tile = 32n x 512m (FULL M) so each block owns a CONTIGUOUS 64KB output
// region. Epilogue goes through a 64KB XOR-swizzled LDS buffer and streams
// out as pure contiguous 1KB-per-wave float4 stores (fill-kernel pattern),
// fixing the 64B-granule/2KB-stride scatter that capped R5/R12 at ~2.3 TB/s.
//
//  - trunc-split x = xh+xl, p = ph+pl (bf16+residual); cross = ph.xh + ph.xl
//    + pl.xh via mfma_f32_16x16x32_bf16 (swapped: A=p so C/D reg-dim = m).
//  - x read exactly once (block covers all m); p (128KB) L2-resident.
//  - Norms in-register (shfl_xor 16/32 reduce; ps redistributed via shfl).
//  - 64KB LDS -> 2 blocks/CU; launch_bounds(256,2).

#define N_PTS 131072
#define M_PROT 512
#define D_DIM 64
#define BN 32

typedef __attribute__((ext_vector_type(8))) short short8;
typedef __attribute__((ext_vector_type(4))) float f32x4;

union FragU { uint u[4]; short8 s; };

// Load 8 contiguous floats, trunc-split to bf16 hi + bf16 lo, accumulate sumsq.
__device__ inline void load_split(const float* p, short8& hi, short8& lo, float& nrm) {
  const float4 a = *reinterpret_cast<const float4*>(p);
  const float4 b = *reinterpret_cast<const float4*>(p + 4);
  const float f[8] = {a.x, a.y, a.z, a.w, b.x, b.y, b.z, b.w};
  FragU H, L;
#pragma unroll
  for (int i = 0; i < 4; ++i) {
    const uint u0 = __float_as_uint(f[2 * i]);
    const uint u1 = __float_as_uint(f[2 * i + 1]);
    H.u[i] = (u0 >> 16) | (u1 & 0xFFFF0000u);
    const float l0 = f[2 * i]     - __uint_as_float(u0 & 0xFFFF0000u);
    const float l1 = f[2 * i + 1] - __uint_as_float(u1 & 0xFFFF0000u);
    L.u[i] = (__float_as_uint(l0) >> 16) | (__float_as_uint(l1) & 0xFFFF0000u);
    nrm = fmaf(f[2 * i], f[2 * i], nrm);
    nrm = fmaf(f[2 * i + 1], f[2 * i + 1], nrm);
  }
  hi = H.s;
  lo = L.s;
}

__global__ __launch_bounds__(256, 2)
void rbf_mfma(const float* __restrict__ x,
              const float* __restrict__ prot,
              float* __restrict__ out) {
  __shared__ float T[BN * M_PROT];  // 64 KB staging tile, XOR-swizzled rows

  const int tid = threadIdx.x;
  const int lane = tid & 63;
  const int w = tid >> 6;       // wave 0..3 owns m in [w*128, w*128+128)
  const int n0 = blockIdx.x * BN;
  const int lr = lane & 15;     // fragment row (p-row m / x-row n)
  const int kg = (lane >> 4) * 8;
  const int m0w = w * 128;

  f32x4 acc[8][2];  // acc[fi(m)][fj(n)]
#pragma unroll
  for (int i = 0; i < 8; ++i)
#pragma unroll
    for (int j = 0; j < 2; ++j) acc[i][j] = (f32x4){0.f, 0.f, 0.f, 0.f};

  float ps_part[8] = {0.f, 0.f, 0.f, 0.f, 0.f, 0.f, 0.f, 0.f};
  float xs_part[2] = {0.f, 0.f};

#pragma unroll
  for (int h = 0; h < 2; ++h) {  // two k=32 halves of D=64
    short8 XH[2], XL[2];
#pragma unroll
    for (int fj = 0; fj < 2; ++fj)
      load_split(x + (size_t)(n0 + fj * 16 + lr) * D_DIM + h * 32 + kg,
                 XH[fj], XL[fj], xs_part[fj]);
#pragma unroll
    for (int fi = 0; fi < 8; ++fi) {
      short8 ph, pl;
      load_split(prot + (size_t)(m0w + fi * 16 + lr) * D_DIM + h * 32 + kg,
                 ph, pl, ps_part[fi]);
#pragma unroll
      for (int fj = 0; fj < 2; ++fj) {
        acc[fi][fj] = __builtin_amdgcn_mfma_f32_16x16x32_bf16(ph, XH[fj], acc[fi][fj], 0, 0, 0);
        acc[fi][fj] = __builtin_amdgcn_mfma_f32_16x16x32_bf16(ph, XL[fj], acc[fi][fj], 0, 0, 0);
        acc[fi][fj] = __builtin_amdgcn_mfma_f32_16x16x32_bf16(pl, XH[fj], acc[fi][fj], 0, 0, 0);
      }
    }
  }

  // ---- norm reductions (full row sums on every lane) ----
#pragma unroll
  for (int fi = 0; fi < 8; ++fi) {
    ps_part[fi] += __shfl_xor(ps_part[fi], 16);
    ps_part[fi] += __shfl_xor(ps_part[fi], 32);
  }
#pragma unroll
  for (int fj = 0; fj < 2; ++fj) {
    xs_part[fj] += __shfl_xor(xs_part[fj], 16);
    xs_part[fj] += __shfl_xor(xs_part[fj], 32);
  }
  const int src = (lane >> 4) * 4;  // reg-dim m offset of this lane

  // ---- epilogue: exp -> swizzled LDS ----
  // C/D layout: col(n)=lane&15, row(m)=(lane>>4)*4+reg.
#pragma unroll
  for (int fi = 0; fi < 8; ++fi) {
    f32x4 psv;
#pragma unroll
    for (int r = 0; r < 4; ++r) psv[r] = __shfl(ps_part[fi], src + r);
#pragma unroll
    for (int fj = 0; fj < 2; ++fj) {
      const f32x4 c = acc[fi][fj];
      const float xsv = xs_part[fj];
      float4 e;
      e.x = __expf(fminf(fmaf(2.f, c[0], -xsv) - psv[0], 0.f));
      e.y = __expf(fminf(fmaf(2.f, c[1], -xsv) - psv[1], 0.f));
      e.z = __expf(fminf(fmaf(2.f, c[2], -xsv) - psv[2], 0.f));
      e.w = __expf(fminf(fmaf(2.f, c[3], -xsv) - psv[3], 0.f));
      const int n_rel = fj * 16 + lr;
      const int m = m0w + fi * 16 + src;
      const int byte = (n_rel * 2048 + m * 4) ^ ((n_rel & 7) << 4);
      *reinterpret_cast<float4*>(reinterpret_cast<char*>(T) + byte) = e;
    }
  }
  __syncthreads();

  // ---- stream out: contiguous 1KB/wave float4 stores (fill pattern) ----
  const size_t outbase = (size_t)n0 * M_PROT;
#pragma unroll
  for (int i = 0; i < 16; ++i) {
    const int fidx = i * 1024 + tid * 4;  // 0..16383 floats
    const int n_rel = fidx >> 9;
    const int byte = (fidx * 4) ^ ((n_rel & 7) << 4);
    const float4 v = *reinterpret_cast<const float4*>(reinterpret_cast<const char*>(T) + byte);
    *reinterpret_cast<float4*>(out + outbase + fidx) = v;
  }
}

extern "C" void kernel_launch(void* const* d_in, const int* in_sizes, int n_in,
                              void* d_out, int out_size, void* d_ws, size_t ws_size,
                              hipStream_t stream) {
  const float* x = (const float*)d_in[0];
  const float* p = (const float*)d_in[1];
  float* out = (float*)d_out;
  (void)in_sizes; (void)n_in; (void)out_size; (void)d_ws; (void)ws_size;
  rbf_mfma<<<N_PTS / BN, 256, 0, stream>>>(x, p, out);
}